// Round 1
// baseline (135.872 us; speedup 1.0000x reference)
//
#include <hip/hip_runtime.h>

#define NROWS 8192
#define KDIM  512
#define SCALE 16.0f
#define EPS   1e-8f

typedef __attribute__((ext_vector_type(8))) short bf16x8;   // 8 bf16 = 4 VGPRs
typedef __attribute__((ext_vector_type(4))) float f32x4;

typedef unsigned int u32;
typedef unsigned short u16;

// ---- round-to-nearest-even f32 -> bf16 (bits) ----
__device__ __forceinline__ u16 f2bf(float f) {
    u32 u = __float_as_uint(f);
    u32 rounding = 0x7FFFu + ((u >> 16) & 1u);
    return (u16)((u + rounding) >> 16);
}

// ---- async global->LDS, 16B per lane (wave-uniform base + lane*16) ----
__device__ __forceinline__ void gload_lds16(const void* g, void* l) {
    __builtin_amdgcn_global_load_lds(
        (const __attribute__((address_space(1))) u32*)g,
        (__attribute__((address_space(3))) u32*)l,
        16, 0, 0);
}

// =====================================================================
// Kernel 1: row-normalize (f32) -> bf16. One wave per row, 4 rows/block.
// rows 0..8191 -> x1 -> o1 ; rows 8192..16383 -> x2 -> o2
// =====================================================================
__global__ __launch_bounds__(256) void norm_cast_kernel(
        const float* __restrict__ x1, const float* __restrict__ x2,
        u16* __restrict__ o1, u16* __restrict__ o2) {
    const int wave = threadIdx.x >> 6;
    const int lane = threadIdx.x & 63;
    int row = blockIdx.x * 4 + wave;          // 0..16383

    const float* src;
    u16* dst;
    if (row < NROWS) { src = x1 + (size_t)row * KDIM;           dst = o1 + (size_t)row * KDIM; }
    else             { src = x2 + (size_t)(row - NROWS) * KDIM; dst = o2 + (size_t)(row - NROWS) * KDIM; }

    // 512 floats / 64 lanes = 8 per lane (two float4)
    const float4* s4 = (const float4*)src + lane * 2;
    float4 a = s4[0];
    float4 b = s4[1];

    float ss = a.x*a.x + a.y*a.y + a.z*a.z + a.w*a.w
             + b.x*b.x + b.y*b.y + b.z*b.z + b.w*b.w;
    #pragma unroll
    for (int off = 32; off; off >>= 1) ss += __shfl_xor(ss, off);

    float inv = 1.0f / fmaxf(sqrtf(ss), EPS);

    u16 h[8];
    h[0] = f2bf(a.x * inv); h[1] = f2bf(a.y * inv);
    h[2] = f2bf(a.z * inv); h[3] = f2bf(a.w * inv);
    h[4] = f2bf(b.x * inv); h[5] = f2bf(b.y * inv);
    h[6] = f2bf(b.z * inv); h[7] = f2bf(b.w * inv);

    uint4 o;
    o.x = (u32)h[0] | ((u32)h[1] << 16);
    o.y = (u32)h[2] | ((u32)h[3] << 16);
    o.z = (u32)h[4] | ((u32)h[5] << 16);
    o.w = (u32)h[6] | ((u32)h[7] << 16);
    *((uint4*)dst + lane) = o;
}

// =====================================================================
// Kernel 2: C[m][n] = SCALE * sum_k A[m][k]*B[n][k]   (both [8192][512] bf16)
// m97 structure: 128x128 tile, BK=32, 4 waves (2x2), 4x4 16x16x32 MFMA frags,
// global_load_lds width=16 staging, linear LDS, ds_read_b128 fragments.
// =====================================================================
#define BM 128
#define BN 128
#define BK 32

__global__ __launch_bounds__(256, 3) void gemm_bt_kernel(
        const u16* __restrict__ A, const u16* __restrict__ B,
        float* __restrict__ C) {
    __shared__ __align__(16) u16 As[BM * BK];   // 8 KB
    __shared__ __align__(16) u16 Bs[BN * BK];   // 8 KB

    // bijective XCD swizzle (nwg = 4096, divisible by 8)
    const int nwg = gridDim.x;
    const int cpx = nwg >> 3;
    const int bid = blockIdx.x;
    const int wg  = (bid & 7) * cpx + (bid >> 3);

    const int tile_n = (wg & 63) * BN;
    const int tile_m = (wg >> 6) * BM;

    const int tid  = threadIdx.x;
    const int wave = tid >> 6;
    const int lane = tid & 63;
    const int wm   = wave >> 1;     // 0..1
    const int wn   = wave & 1;      // 0..1

    // staging: 4 lanes per 32-elem row segment, 64 rows per pass, 2 passes
    const int srow = tid >> 2;            // 0..63
    const int scol = (tid & 3) * 8;       // 0,8,16,24

    // fragment addressing (16x16x32: row = lane&15, k = 8*(lane>>4)+j)
    const int fr = lane & 15;
    const int fk = (lane >> 4) * 8;

    f32x4 acc[4][4] = {};

    for (int k0 = 0; k0 < KDIM; k0 += BK) {
        __syncthreads();   // previous compute done before overwriting LDS
        #pragma unroll
        for (int it = 0; it < 2; ++it) {
            const int r = srow + it * 64;
            gload_lds16(A + (size_t)(tile_m + r) * KDIM + k0 + scol, &As[r * BK + scol]);
            gload_lds16(B + (size_t)(tile_n + r) * KDIM + k0 + scol, &Bs[r * BK + scol]);
        }
        __syncthreads();   // compiler emits vmcnt(0) drain before barrier

        bf16x8 af[4], bfr[4];
        #pragma unroll
        for (int mi = 0; mi < 4; ++mi)
            af[mi] = *(const bf16x8*)&As[(wm * 64 + mi * 16 + fr) * BK + fk];
        #pragma unroll
        for (int ni = 0; ni < 4; ++ni)
            bfr[ni] = *(const bf16x8*)&Bs[(wn * 64 + ni * 16 + fr) * BK + fk];

        #pragma unroll
        for (int mi = 0; mi < 4; ++mi)
            #pragma unroll
            for (int ni = 0; ni < 4; ++ni)
                acc[mi][ni] = __builtin_amdgcn_mfma_f32_16x16x32_bf16(
                    af[mi], bfr[ni], acc[mi][ni], 0, 0, 0);
    }

    // epilogue: D mapping (verified m89): n = lane&15, m = (lane>>4)*4 + reg
    const int r0 = (lane >> 4) * 4;
    const int cn = lane & 15;
    #pragma unroll
    for (int mi = 0; mi < 4; ++mi) {
        #pragma unroll
        for (int ni = 0; ni < 4; ++ni) {
            size_t base = (size_t)(tile_m + wm * 64 + mi * 16 + r0) * NROWS
                        + (size_t)(tile_n + wn * 64 + ni * 16 + cn);
            #pragma unroll
            for (int r = 0; r < 4; ++r)
                C[base + (size_t)r * NROWS] = SCALE * acc[mi][ni][r];
        }
    }
}

extern "C" void kernel_launch(void* const* d_in, const int* in_sizes, int n_in,
                              void* d_out, int out_size, void* d_ws, size_t ws_size,
                              hipStream_t stream) {
    const float* x1 = (const float*)d_in[0];
    const float* x2 = (const float*)d_in[1];
    float* out = (float*)d_out;

    u16* a_bf = (u16*)d_ws;                          // 8 MB
    u16* b_bf = a_bf + (size_t)NROWS * KDIM;         // 8 MB

    norm_cast_kernel<<<4096, 256, 0, stream>>>(x1, x2, a_bf, b_bf);

    const int grid = (NROWS / BM) * (NROWS / BN);    // 4096
    gemm_bt_kernel<<<grid, 256, 0, stream>>>(a_bf, b_bf, out);
}

// Round 2
// 116.134 us; speedup vs baseline: 1.1700x; 1.1700x over previous
//
#include <hip/hip_runtime.h>

#define NROWS 8192
#define KDIM  512
#define SCALEF 16.0f
#define EPSF  1e-8f

typedef __attribute__((ext_vector_type(8))) short bf16x8;   // 8 bf16 = 4 VGPRs
typedef __attribute__((ext_vector_type(4))) float f32x4;

typedef unsigned int u32;
typedef unsigned short u16;

// ---- round-to-nearest-even f32 -> bf16 (bits) ----
__device__ __forceinline__ u16 f2bf(float f) {
    u32 u = __float_as_uint(f);
    u32 rounding = 0x7FFFu + ((u >> 16) & 1u);
    return (u16)((u + rounding) >> 16);
}

// ---- async global->LDS, 16B per lane (wave-uniform base + lane*16) ----
__device__ __forceinline__ void gload_lds16(const void* g, void* l) {
    __builtin_amdgcn_global_load_lds(
        (const __attribute__((address_space(1))) u32*)g,
        (__attribute__((address_space(3))) u32*)l,
        16, 0, 0);
}

// =====================================================================
// Kernel 1: row-normalize (f32) -> bf16. One wave per row, 4 rows/block.
// =====================================================================
__global__ __launch_bounds__(256) void norm_cast_kernel(
        const float* __restrict__ x1, const float* __restrict__ x2,
        u16* __restrict__ o1, u16* __restrict__ o2) {
    const int wave = threadIdx.x >> 6;
    const int lane = threadIdx.x & 63;
    int row = blockIdx.x * 4 + wave;          // 0..16383

    const float* src;
    u16* dst;
    if (row < NROWS) { src = x1 + (size_t)row * KDIM;           dst = o1 + (size_t)row * KDIM; }
    else             { src = x2 + (size_t)(row - NROWS) * KDIM; dst = o2 + (size_t)(row - NROWS) * KDIM; }

    const float4* s4 = (const float4*)src + lane * 2;
    float4 a = s4[0];
    float4 b = s4[1];

    float ss = a.x*a.x + a.y*a.y + a.z*a.z + a.w*a.w
             + b.x*b.x + b.y*b.y + b.z*b.z + b.w*b.w;
    #pragma unroll
    for (int off = 32; off; off >>= 1) ss += __shfl_xor(ss, off);

    float inv = 1.0f / fmaxf(sqrtf(ss), EPSF);

    u16 h[8];
    h[0] = f2bf(a.x * inv); h[1] = f2bf(a.y * inv);
    h[2] = f2bf(a.z * inv); h[3] = f2bf(a.w * inv);
    h[4] = f2bf(b.x * inv); h[5] = f2bf(b.y * inv);
    h[6] = f2bf(b.z * inv); h[7] = f2bf(b.w * inv);

    uint4 o;
    o.x = (u32)h[0] | ((u32)h[1] << 16);
    o.y = (u32)h[2] | ((u32)h[3] << 16);
    o.z = (u32)h[4] | ((u32)h[5] << 16);
    o.w = (u32)h[6] | ((u32)h[7] << 16);
    *((uint4*)dst + lane) = o;
}

// =====================================================================
// Kernel 2: 256x256 tile, BK=64, 8 waves (2Mx4N), 8-phase schedule,
// counted vmcnt(6), st XOR-swizzle, setprio around MFMA clusters.
// C[m][n] = SCALE * sum_k A[m][k]*B[n][k], A,B bf16 [8192][512].
//
// LDS (128 KiB): buf{0,1} x { A: 256 rows x 128B @ +0, B: 256 x 128B @ +32768 }
// tile t lives in buf[t&1] (even->0, odd->1).
// Logical (row, colbyte c) stored at LDS row*128 + (c ^ ((row&7)<<4))
// via linear gload_lds dest + inverse-swizzled GLOBAL source (both-sides rule).
//
// Per K-tile, 4 phases = C-quadrants (mh,nh): (0,0),(0,1),(1,1),(1,0).
// Consumption groups: A group g = rows with bit6==g (freed after quad mh=g
// read); B group g = rows with bit5==g. One half-group staged per phase
// (2 gload_lds/thread), always into a region consumed >=1 phase earlier.
// =====================================================================

__global__ __launch_bounds__(512, 2) void gemm_bt_kernel(
        const u16* __restrict__ A, const u16* __restrict__ B,
        float* __restrict__ C) {
    __shared__ __align__(1024) char lds[131072];

    // bijective XCD swizzle (nwg = 1024, divisible by 8)
    const int nwg = gridDim.x;
    const int bid = blockIdx.x;
    const int wg  = (bid & 7) * (nwg >> 3) + (bid >> 3);
    const int tile_m = (wg >> 5) << 8;
    const int tile_n = (wg & 31) << 8;

    const int tid  = threadIdx.x;
    const int wid  = tid >> 6;
    const int lane = tid & 63;
    const int wm   = wid >> 2;      // 0..1  (M)
    const int wn   = wid & 3;       // 0..3  (N)
    const int fr   = lane & 15;
    const int q    = lane >> 4;

    // staging constants: thread tid covers LDS bytes it*8192 + tid*16
    const int s_rl0 = tid >> 3;           // 0..63
    const int s_cl  = (tid & 7) << 4;     // 0..112

    // ds-read constants
    const int xr     = (fr & 7) << 4;
    const int colsw0 = (q * 16) ^ xr;          // kk=0 fragment col (swizzled)
    const int colsw1 = (64 + q * 16) ^ xr;     // kk=1
    const int aRow   = ((wm << 7) + fr) << 7;            // byte row base in A region
    const int bRow   = (((wn << 6) + fr) << 7) + 32768;  // byte row base in B region

    f32x4  acc[8][4] = {};
    bf16x8 af[4][2];   // current A half (4 mi x 2 kk)
    bf16x8 bf[4][2];   // full B tile   (4 ni x 2 kk)

// stage one half-group: ISB selects A/B, BUF buffer, G group bit, T K-tile idx
#define STAGE(ISB, BUF, G, T) do {                                             \
    const u16* _g  = (ISB) ? B : A;                                            \
    const int _grow = (ISB) ? tile_n : tile_m;                                 \
    char* _l = lds + (BUF) * 65536 + ((ISB) ? 32768 : 0);                      \
    _Pragma("unroll")                                                          \
    for (int _it = 0; _it < 2; ++_it) {                                        \
        int _rl  = _it * 64 + s_rl0;                                           \
        int _row = (ISB) ? (((_rl >> 5) << 6) + ((G) << 5) + (_rl & 31))       \
                         : (((_rl >> 6) << 7) + ((G) << 6) + (_rl & 63));      \
        int _csrc = s_cl ^ ((_row & 7) << 4);                                  \
        gload_lds16((const char*)_g + ((size_t)(_grow + _row) * KDIM + (size_t)(T) * 64) * 2 + _csrc, \
                    _l + _row * 128 + s_cl);                                   \
    }                                                                          \
} while (0)

#define LOAD_A(BUF, MH) do {                                                   \
    char* _l = lds + (BUF) * 65536;                                            \
    _Pragma("unroll")                                                          \
    for (int _m = 0; _m < 4; ++_m) {                                           \
        af[_m][0] = *(const bf16x8*)(_l + aRow + ((MH) * 4 + _m) * 2048 + colsw0); \
        af[_m][1] = *(const bf16x8*)(_l + aRow + ((MH) * 4 + _m) * 2048 + colsw1); \
    }                                                                          \
} while (0)

#define LOAD_B(BUF, NH) do {                                                   \
    char* _l = lds + (BUF) * 65536;                                            \
    _Pragma("unroll")                                                          \
    for (int _n = 0; _n < 2; ++_n) {                                           \
        bf[(NH) * 2 + _n][0] = *(const bf16x8*)(_l + bRow + ((NH) * 2 + _n) * 2048 + colsw0); \
        bf[(NH) * 2 + _n][1] = *(const bf16x8*)(_l + bRow + ((NH) * 2 + _n) * 2048 + colsw1); \
    }                                                                          \
} while (0)

#define MFMA_Q(MH, NH) do {                                                    \
    __builtin_amdgcn_s_setprio(1);                                             \
    _Pragma("unroll")                                                          \
    for (int _m = 0; _m < 4; ++_m)                                             \
    _Pragma("unroll")                                                          \
    for (int _n = 0; _n < 2; ++_n)                                             \
    _Pragma("unroll")                                                          \
    for (int _kk = 0; _kk < 2; ++_kk)                                          \
        acc[(MH) * 4 + _m][(NH) * 2 + _n] = __builtin_amdgcn_mfma_f32_16x16x32_bf16( \
            af[_m][_kk], bf[(NH) * 2 + _n][_kk], acc[(MH) * 4 + _m][(NH) * 2 + _n], 0, 0, 0); \
    __builtin_amdgcn_s_setprio(0);                                             \
} while (0)

#define BAR()   __builtin_amdgcn_s_barrier()
#define LGKM0() asm volatile("s_waitcnt lgkmcnt(0)")

    // ---- prologue: tile0 (all 4 groups) + tile1 (Ag0,Bg0,Bg1) = 14 loads ----
    STAGE(0, 0, 0, 0); STAGE(1, 0, 0, 0); STAGE(1, 0, 1, 0); STAGE(0, 0, 1, 0);
    STAGE(0, 1, 0, 1); STAGE(1, 1, 0, 1); STAGE(1, 1, 1, 1);
    asm volatile("s_waitcnt vmcnt(6)" ::: "memory");   // tile0 complete
    BAR();

    // ---- steady iterations: tiles (2i, 2i+1), prefetch (2i+2, 2i+3) ----
    for (int i = 0; i < 3; ++i) {
        const int t0 = 2 * i, t1 = 2 * i + 1;
        // PH1: quad(0,0) of tile t0 (buf0)
        LOAD_A(0, 0); LOAD_B(0, 0);
        STAGE(0, 1, 1, t1);                    // buf1.Ag1 <- tile t1
        asm volatile("s_waitcnt lgkmcnt(8)");
        BAR(); LGKM0(); MFMA_Q(0, 0); BAR();
        // PH2: quad(0,1)
        LOAD_B(0, 1);
        STAGE(0, 0, 0, t0 + 2);                // buf0.Ag0 <- tile t0+2
        BAR(); LGKM0(); MFMA_Q(0, 1); BAR();
        // PH3: quad(1,1)
        LOAD_A(0, 1);
        STAGE(1, 0, 0, t0 + 2);                // buf0.Bg0
        BAR(); LGKM0(); MFMA_Q(1, 1); BAR();
        // PH4: quad(1,0) — vmcnt once per K-tile
        STAGE(1, 0, 1, t0 + 2);                // buf0.Bg1
        asm volatile("s_waitcnt vmcnt(6)" ::: "memory");   // tile t1 complete
        BAR(); MFMA_Q(1, 0); BAR();
        // PH5: quad(0,0) of tile t1 (buf1)
        LOAD_A(1, 0); LOAD_B(1, 0);
        STAGE(0, 0, 1, t0 + 2);                // buf0.Ag1
        asm volatile("s_waitcnt lgkmcnt(8)");
        BAR(); LGKM0(); MFMA_Q(0, 0); BAR();
        // PH6: quad(0,1)
        LOAD_B(1, 1);
        STAGE(0, 1, 0, t1 + 2);                // buf1.Ag0 <- tile t1+2
        BAR(); LGKM0(); MFMA_Q(0, 1); BAR();
        // PH7: quad(1,1)
        LOAD_A(1, 1);
        STAGE(1, 1, 0, t1 + 2);                // buf1.Bg0
        BAR(); LGKM0(); MFMA_Q(1, 1); BAR();
        // PH8: quad(1,0)
        STAGE(1, 1, 1, t1 + 2);                // buf1.Bg1
        asm volatile("s_waitcnt vmcnt(6)" ::: "memory");   // tile t0+2 complete
        BAR(); MFMA_Q(1, 0); BAR();
    }

    // ---- tail: tiles 6 (buf0) and 7 (buf1), no further prefetch ----
    LOAD_A(0, 0); LOAD_B(0, 0);
    STAGE(0, 1, 1, 7);                         // buf1.Ag1 <- tile 7 (last load)
    BAR(); LGKM0(); MFMA_Q(0, 0); BAR();
    LOAD_B(0, 1);
    BAR(); LGKM0(); MFMA_Q(0, 1); BAR();
    LOAD_A(0, 1);
    BAR(); LGKM0(); MFMA_Q(1, 1); BAR();
    asm volatile("s_waitcnt vmcnt(0)" ::: "memory");       // tile 7 complete
    BAR(); MFMA_Q(1, 0); BAR();
    LOAD_A(1, 0); LOAD_B(1, 0);
    BAR(); LGKM0(); MFMA_Q(0, 0); BAR();
    LOAD_B(1, 1);
    BAR(); LGKM0(); MFMA_Q(0, 1); BAR();
    LOAD_A(1, 1);
    BAR(); LGKM0(); MFMA_Q(1, 1); BAR();
    MFMA_Q(1, 0);

    // ---- epilogue: D mapping n = lane&15, m = (lane>>4)*4 + reg ----
    const int r0 = q * 4;
    #pragma unroll
    for (int mi = 0; mi < 8; ++mi) {
        #pragma unroll
        for (int ni = 0; ni < 4; ++ni) {
            size_t base = (size_t)(tile_m + wm * 128 + mi * 16 + r0) * NROWS
                        + (size_t)(tile_n + wn * 64 + ni * 16 + fr);
            #pragma unroll
            for (int r = 0; r < 4; ++r)
                C[base + (size_t)r * NROWS] = SCALEF * acc[mi][ni][r];
        }
    }

#undef STAGE
#undef LOAD_A
#undef LOAD_B
#undef MFMA_Q
#undef BAR
#undef LGKM0
}

extern "C" void kernel_launch(void* const* d_in, const int* in_sizes, int n_in,
                              void* d_out, int out_size, void* d_ws, size_t ws_size,
                              hipStream_t stream) {
    const float* x1 = (const float*)d_in[0];
    const float* x2 = (const float*)d_in[1];
    float* out = (float*)d_out;

    u16* a_bf = (u16*)d_ws;                          // 8 MB
    u16* b_bf = a_bf + (size_t)NROWS * KDIM;         // 8 MB

    norm_cast_kernel<<<4096, 256, 0, stream>>>(x1, x2, a_bf, b_bf);

    const int grid = (NROWS / 256) * (NROWS / 256);  // 1024
    gemm_bt_kernel<<<grid, 512, 0, stream>>>(a_bf, b_bf, out);
}